// Round 1
// baseline (2668.162 us; speedup 1.0000x reference)
//
#include <hip/hip_runtime.h>
#include <math.h>

// Problem constants
#define B_ 4
#define S_ 2048
#define D_ 1024
#define H_ 16
#define DK_ 64
// 1/sqrt(DK)
#define SCALE_ 0.125f
#define THETA_ 10000.0f

// ---------------------------------------------------------------------------
// GEMM: Y = X @ W^T
//   X: [M, K] row-major (M = B*S, K = D)
//   W: [N, K] row-major (N = D)   (einsum 'bsd,od->bso' => y[m,o] = sum_d x*W[o,d])
// MODE 0: write Y[m*D + n]                      (final Wo projection)
// MODE 1: write Y[((b*H+h)*S+s)*DK + dk]        (V, [B,H,S,DK] layout)
// MODE 2: same as 1 but with interleaved RoPE   (Q, K)
// Tile: 64x64, BK=16, block 16x16 threads, 4x4 micro-tile per thread.
// ---------------------------------------------------------------------------
template <int MODE>
__global__ __launch_bounds__(256) void gemm_proj(const float* __restrict__ X,
                                                 const float* __restrict__ W,
                                                 const int* __restrict__ pos,
                                                 float* __restrict__ Y) {
    __shared__ float As[64][17];
    __shared__ float Bs[64][17];

    const int tx = threadIdx.x;        // 0..15
    const int ty = threadIdx.y;        // 0..15
    const int t  = ty * 16 + tx;       // 0..255
    const int m0 = blockIdx.y * 64;
    const int n0 = blockIdx.x * 64;

    const int lr = t >> 4;   // 0..15 (row within 16-row slab)
    const int lc = t & 15;   // 0..15 (k within tile)

    float c[4][4] = {};

    for (int k0 = 0; k0 < D_; k0 += 16) {
        // Stage 64x16 tiles of X and W (coalesced along k).
#pragma unroll
        for (int i = 0; i < 4; ++i) {
            As[lr + 16 * i][lc] = X[(size_t)(m0 + lr + 16 * i) * D_ + k0 + lc];
            Bs[lr + 16 * i][lc] = W[(size_t)(n0 + lr + 16 * i) * D_ + k0 + lc];
        }
        __syncthreads();
#pragma unroll
        for (int kk = 0; kk < 16; ++kk) {
            float a[4], b[4];
#pragma unroll
            for (int i = 0; i < 4; ++i) a[i] = As[ty * 4 + i][kk];
#pragma unroll
            for (int j = 0; j < 4; ++j) b[j] = Bs[tx * 4 + j][kk];
#pragma unroll
            for (int i = 0; i < 4; ++i)
#pragma unroll
                for (int j = 0; j < 4; ++j) c[i][j] = fmaf(a[i], b[j], c[i][j]);
        }
        __syncthreads();
    }

    // Epilogue
#pragma unroll
    for (int i = 0; i < 4; ++i) {
        const int m  = m0 + ty * 4 + i;
        const int b  = m / S_;
        const int s  = m % S_;
        if (MODE == 0) {
#pragma unroll
            for (int j = 0; j < 4; ++j) {
                const int n = n0 + tx * 4 + j;
                Y[(size_t)m * D_ + n] = c[i][j];
            }
        } else if (MODE == 1) {
#pragma unroll
            for (int j = 0; j < 4; ++j) {
                const int n  = n0 + tx * 4 + j;
                const int h  = n >> 6;       // n / DK
                const int dk = n & 63;       // n % DK
                Y[(((size_t)b * H_ + h) * S_ + s) * DK_ + dk] = c[i][j];
            }
        } else {
            const float p = (float)pos[s];
#pragma unroll
            for (int j = 0; j < 4; j += 2) {
                const int n  = n0 + tx * 4 + j;   // even
                const int h  = n >> 6;
                const int dk = n & 63;            // even
                // freq = THETA^(-dk/DK) for even dk (pair index p_idx = dk/2)
                const float freq  = powf(THETA_, -(float)dk / (float)DK_);
                const float ang   = p * freq;
                const float cs    = cosf(ang);
                const float sn    = sinf(ang);
                const float x1    = c[i][j];
                const float x2    = c[i][j + 1];
                const float r1    = x1 * cs - x2 * sn;
                const float r2    = x2 * cs + x1 * sn;
                float* dst = &Y[(((size_t)b * H_ + h) * S_ + s) * DK_ + dk];
                dst[0] = r1;
                dst[1] = r2;
            }
        }
    }
}

// ---------------------------------------------------------------------------
// Causal flash attention, fp32.
// Q,K,V: [B,H,S,DK].  O: [B,S,D] (head-major columns h*DK+dk).
// Block: 128 threads, each owns one query row. Grid: (S/128, B*H).
// K/V staged in LDS in 64-row tiles; online softmax with lazy rescale.
// ---------------------------------------------------------------------------
__global__ __launch_bounds__(128) void attn_fwd(const float* __restrict__ Q,
                                                const float* __restrict__ K,
                                                const float* __restrict__ V,
                                                float* __restrict__ O) {
    __shared__ float Ks[64][64];
    __shared__ float Vs[64][64];

    const int t  = threadIdx.x;          // 0..127
    const int q0 = blockIdx.x * 128;
    const int bh = blockIdx.y;           // b*H + h
    const int q  = q0 + t;

    const float* Qrow = Q + ((size_t)bh * S_ + q) * DK_;
    float4 qr[16];
#pragma unroll
    for (int i = 0; i < 16; ++i) qr[i] = reinterpret_cast<const float4*>(Qrow)[i];

    float acc[64] = {};
    float m = -INFINITY, l = 0.0f;

    const float* Kbase = K + (size_t)bh * S_ * DK_;
    const float* Vbase = V + (size_t)bh * S_ * DK_;
    const int ktiles = q0 / 64 + 2;      // covers k <= q0+127

    for (int kt = 0; kt < ktiles; ++kt) {
        // Cooperative stage: 64x64 floats = 1024 float4, 128 threads -> 8 each
        const float4* Ksrc = reinterpret_cast<const float4*>(Kbase + (size_t)kt * 64 * DK_);
        const float4* Vsrc = reinterpret_cast<const float4*>(Vbase + (size_t)kt * 64 * DK_);
        float4* Kdst = reinterpret_cast<float4*>(&Ks[0][0]);
        float4* Vdst = reinterpret_cast<float4*>(&Vs[0][0]);
#pragma unroll
        for (int i = 0; i < 8; ++i) {
            Kdst[i * 128 + t] = Ksrc[i * 128 + t];
            Vdst[i * 128 + t] = Vsrc[i * 128 + t];
        }
        __syncthreads();

        int kmax = q - kt * 64 + 1;              // causal: k <= q
        if (kmax > 64) kmax = 64;
        for (int kk = 0; kk < kmax; ++kk) {
            const float4* Krow = reinterpret_cast<const float4*>(&Ks[kk][0]);
            float dot = 0.0f;
#pragma unroll
            for (int i = 0; i < 16; ++i) {
                float4 kv = Krow[i];
                dot = fmaf(qr[i].x, kv.x, dot);
                dot = fmaf(qr[i].y, kv.y, dot);
                dot = fmaf(qr[i].z, kv.z, dot);
                dot = fmaf(qr[i].w, kv.w, dot);
            }
            const float sc = dot * SCALE_;
            if (sc > m) {
                const float corr = __expf(m - sc);   // first iter: exp(-inf)=0
                l *= corr;
#pragma unroll
                for (int d = 0; d < 64; ++d) acc[d] *= corr;
                m = sc;
            }
            const float p = __expf(sc - m);
            l += p;
            const float4* Vrow = reinterpret_cast<const float4*>(&Vs[kk][0]);
#pragma unroll
            for (int d = 0; d < 16; ++d) {
                float4 vv = Vrow[d];
                acc[d * 4 + 0] = fmaf(p, vv.x, acc[d * 4 + 0]);
                acc[d * 4 + 1] = fmaf(p, vv.y, acc[d * 4 + 1]);
                acc[d * 4 + 2] = fmaf(p, vv.z, acc[d * 4 + 2]);
                acc[d * 4 + 3] = fmaf(p, vv.w, acc[d * 4 + 3]);
            }
        }
        __syncthreads();
    }

    const float inv = 1.0f / l;
    const int b = bh / H_;
    const int h = bh % H_;
    float* Orow = O + ((size_t)b * S_ + q) * D_ + h * DK_;
#pragma unroll
    for (int d = 0; d < 64; ++d) Orow[d] = acc[d] * inv;
}

// ---------------------------------------------------------------------------
// Launch.  d_in: x, token_positions, Wq, Wk, Wv, Wo
// Workspace layout (floats): Q | K | V | attn_out, each B*S*D = 8388608 elems
// => needs 128 MiB of d_ws.
// ---------------------------------------------------------------------------
extern "C" void kernel_launch(void* const* d_in, const int* in_sizes, int n_in,
                              void* d_out, int out_size, void* d_ws, size_t ws_size,
                              hipStream_t stream) {
    const float* x  = (const float*)d_in[0];
    const int*   tp = (const int*)d_in[1];
    const float* Wq = (const float*)d_in[2];
    const float* Wk = (const float*)d_in[3];
    const float* Wv = (const float*)d_in[4];
    const float* Wo = (const float*)d_in[5];
    float* out = (float*)d_out;

    float* ws = (float*)d_ws;
    const size_t SZ = (size_t)B_ * S_ * D_;   // 8388608
    float* Qb = ws;
    float* Kb = ws + SZ;
    float* Vb = ws + 2 * SZ;
    float* Ao = ws + 3 * SZ;

    dim3 gblk(D_ / 64, (B_ * S_) / 64);       // (16, 128)
    dim3 gthr(16, 16);
    gemm_proj<2><<<gblk, gthr, 0, stream>>>(x, Wq, tp, Qb);
    gemm_proj<2><<<gblk, gthr, 0, stream>>>(x, Wk, tp, Kb);
    gemm_proj<1><<<gblk, gthr, 0, stream>>>(x, Wv, tp, Vb);

    attn_fwd<<<dim3(S_ / 128, B_ * H_), 128, 0, stream>>>(Qb, Kb, Vb, Ao);

    gemm_proj<0><<<gblk, gthr, 0, stream>>>(Ao, Wo, tp, out);
}

// Round 2
// 326.297 us; speedup vs baseline: 8.1771x; 8.1771x over previous
//
#include <hip/hip_runtime.h>
#include <math.h>

#define B_ 4
#define S_ 2048
#define D_ 1024
#define H_ 16
#define DK_ 64
#define SCALE_ 0.125f
#define THETA_ 10000.0f

typedef unsigned short ushort_t;
typedef __attribute__((ext_vector_type(8))) short bf16x8;   // 8 bf16 (4 VGPRs)
typedef __attribute__((ext_vector_type(4))) float f32x4;    // MFMA C/D

__device__ __forceinline__ ushort_t f2bf(float f) {
    union { float f; unsigned u; } v; v.f = f;
    unsigned r = (v.u + 0x7FFFu + ((v.u >> 16) & 1u)) >> 16;   // RNE
    return (ushort_t)r;
}

#define GLOAD_LDS16(gptr, lptr)                                                   \
    __builtin_amdgcn_global_load_lds(                                             \
        (const __attribute__((address_space(1))) unsigned int*)(gptr),            \
        (__attribute__((address_space(3))) unsigned int*)(lptr), 16, 0, 0)

// ---------------------------------------------------------------------------
// fp32 -> bf16 cast, vectorized (4 elems/thread)
// ---------------------------------------------------------------------------
__global__ __launch_bounds__(256) void cast_f32_bf16(const float* __restrict__ in,
                                                     ushort_t* __restrict__ out, int n) {
    int i = (blockIdx.x * 256 + threadIdx.x) * 4;
    if (i >= n) return;
    float4 v = *reinterpret_cast<const float4*>(in + i);
    unsigned lo = (unsigned)f2bf(v.x) | ((unsigned)f2bf(v.y) << 16);
    unsigned hi = (unsigned)f2bf(v.z) | ((unsigned)f2bf(v.w) << 16);
    uint2 u; u.x = lo; u.y = hi;
    *reinterpret_cast<uint2*>(out + i) = u;
}

// ---------------------------------------------------------------------------
// RoPE cos/sin table: tab[s*32 + p] = (cos(pos[s]*f_p), sin(pos[s]*f_p))
// f_p = THETA^(-2p/64)
// ---------------------------------------------------------------------------
__global__ __launch_bounds__(256) void build_rope(const int* __restrict__ pos,
                                                  float2* __restrict__ tab) {
    int i = blockIdx.x * 256 + threadIdx.x;    // 0 .. S*32-1
    int s = i >> 5, p = i & 31;
    float freq = powf(THETA_, -2.0f * (float)p / 64.0f);
    float a = (float)pos[s] * freq;
    tab[i] = make_float2(cosf(a), sinf(a));
}

// ---------------------------------------------------------------------------
// bf16 MFMA GEMM: Y = A(bf16 [M][K]) @ W(bf16 [N][K])^T, M=8192,N=1024,K=1024
// m97 structure: 128x128 tile, BK=32, 4 waves, global_load_lds, 2 barriers.
// MODE 0: write fp32 Y[m*D+n]
// MODE 1: write bf16 Y[b,h,s,dk]          (V)
// MODE 2: MODE1 + interleaved RoPE via table (Q,K)
// ---------------------------------------------------------------------------
template <int MODE>
__global__ __launch_bounds__(256) void gemm_bf16(const ushort_t* __restrict__ A,
                                                 const ushort_t* __restrict__ W,
                                                 const float2* __restrict__ tab,
                                                 float* __restrict__ outF,
                                                 ushort_t* __restrict__ outB) {
    __shared__ ushort_t Asl[128 * 32];
    __shared__ ushort_t Bsl[128 * 32];

    const int t = threadIdx.x;
    const int lane = t & 63;
    const int w = t >> 6;
    const int lr = lane & 15;
    const int lg = lane >> 4;

    // XCD-aware swizzle over 512 blocks (512 % 8 == 0 -> bijective)
    const int bid = blockIdx.x;
    const int swz = (bid & 7) * 64 + (bid >> 3);
    const int mt = swz >> 3;          // 0..63
    const int nt = swz & 7;           // 0..7
    const int m0 = mt * 128;
    const int n0 = nt * 128;

    const int wr = w >> 1;            // wave row (0..1)
    const int wc = w & 1;             // wave col (0..1)

    f32x4 acc[4][4] = {};

    for (int k0 = 0; k0 < D_; k0 += 32) {
#pragma unroll
        for (int i = 0; i < 2; ++i) {
            const int off = w * 2048 + i * 1024 + lane * 16;   // byte in 128x32 bf16 tile
            const int row = off >> 6;
            const int col = (off & 63) >> 1;
            GLOAD_LDS16(A + (size_t)(m0 + row) * D_ + k0 + col,
                        Asl + (w * 1024 + i * 512));
            GLOAD_LDS16(W + (size_t)(n0 + row) * D_ + k0 + col,
                        Bsl + (w * 1024 + i * 512));
        }
        __syncthreads();

        bf16x8 af[4], bfr[4];
#pragma unroll
        for (int x = 0; x < 4; ++x) {
            af[x]  = *reinterpret_cast<const bf16x8*>(&Asl[(wr * 64 + x * 16 + lr) * 32 + lg * 8]);
            bfr[x] = *reinterpret_cast<const bf16x8*>(&Bsl[(wc * 64 + x * 16 + lr) * 32 + lg * 8]);
        }
#pragma unroll
        for (int mi = 0; mi < 4; ++mi)
#pragma unroll
            for (int ni = 0; ni < 4; ++ni)
                acc[mi][ni] = __builtin_amdgcn_mfma_f32_16x16x32_bf16(af[mi], bfr[ni], acc[mi][ni], 0, 0, 0);
        __syncthreads();
    }

    // Epilogue.  C layout: col = lane&15, row = (lane>>4)*4 + reg
#pragma unroll
    for (int mi = 0; mi < 4; ++mi) {
#pragma unroll
        for (int r = 0; r < 4; ++r) {
            const int m = m0 + wr * 64 + mi * 16 + lg * 4 + r;
            const int bb = m >> 11;            // m / S
            const int s = m & (S_ - 1);
#pragma unroll
            for (int ni = 0; ni < 4; ++ni) {
                const int n = n0 + wc * 64 + ni * 16 + lr;
                float v = acc[mi][ni][r];
                if (MODE == 0) {
                    outF[(size_t)m * D_ + n] = v;
                } else {
                    const int h = n >> 6, dk = n & 63;
                    if (MODE == 2) {
                        const float2 cs = tab[s * 32 + (dk >> 1)];
                        const float part = __shfl_xor(v, 1, 64);
                        v = (dk & 1) ? fmaf(v, cs.x, part * cs.y)
                                     : fmaf(v, cs.x, -part * cs.y);
                    }
                    outB[(((size_t)bb * H_ + h) * S_ + s) * DK_ + dk] = f2bf(v);
                }
            }
        }
    }
}

// ---------------------------------------------------------------------------
// MFMA flash attention (causal). Q,K,V bf16 [B,H,S,DK]. O bf16 [B,S,D].
// Block = 4 waves; wave w owns 16 query rows. KV tiles of 64 staged in LDS:
// K row-major [64][72], V transposed Vt[dk][kv] [64][72], P via padded LDS.
// ---------------------------------------------------------------------------
#define LDK 72

__global__ __launch_bounds__(256) void attn_mfma(const ushort_t* __restrict__ Q,
                                                 const ushort_t* __restrict__ K,
                                                 const ushort_t* __restrict__ V,
                                                 ushort_t* __restrict__ O) {
    __shared__ ushort_t Ks[64 * LDK];
    __shared__ ushort_t Vt[64 * LDK];
    __shared__ ushort_t Pl[4 * 16 * LDK];

    const int t = threadIdx.x;
    const int lane = t & 63;
    const int w = t >> 6;
    const int lr = lane & 15;
    const int lg = lane >> 4;

    // XCD swizzle over 2048 blocks: 8 heads' KV per XCD (~4 MB L2 footprint)
    const int bid = blockIdx.x;
    const int swz = (bid & 7) * 256 + (bid >> 3);
    const int bh = swz >> 5;          // 0..63
    const int qt = swz & 31;          // 0..31
    const int q0 = qt * 64;

    // Q fragments (A-operand), rows q0 + w*16 + lr, k = kf*32 + lg*8
    const ushort_t* Qbase = Q + ((size_t)bh * S_ + q0 + w * 16) * DK_;
    bf16x8 qf[2];
    qf[0] = *reinterpret_cast<const bf16x8*>(Qbase + (size_t)lr * DK_ + lg * 8);
    qf[1] = *reinterpret_cast<const bf16x8*>(Qbase + (size_t)lr * DK_ + 32 + lg * 8);

    f32x4 acc[4] = {};                 // O fragments over dk (4 x 16)
    float mrow[4], lrow[4];
#pragma unroll
    for (int r = 0; r < 4; ++r) { mrow[r] = -INFINITY; lrow[r] = 0.0f; }

    const ushort_t* Kbase = K + (size_t)bh * S_ * DK_;
    const ushort_t* Vbase = V + (size_t)bh * S_ * DK_;
    const int ntiles = q0 / 64 + 1;

    for (int kt = 0; kt < ntiles; ++kt) {
        // ---- stage K (row-major) and V (transposed) ----
        {
            const int krow = t >> 3;                  // 0..31
            const int kc8 = (t & 7) * 8;
#pragma unroll
            for (int it = 0; it < 2; ++it) {
                const int r2 = krow + it * 32;
                bf16x8 kv8 = *reinterpret_cast<const bf16x8*>(Kbase + ((size_t)(kt * 64 + r2)) * DK_ + kc8);
                *reinterpret_cast<bf16x8*>(&Ks[r2 * LDK + kc8]) = kv8;
            }
            const int vc8 = (t >> 5) * 8;             // dk group
            const int kv2 = (t & 31) * 2;             // kv row pair
            bf16x8 v0 = *reinterpret_cast<const bf16x8*>(Vbase + ((size_t)(kt * 64 + kv2)) * DK_ + vc8);
            bf16x8 v1 = *reinterpret_cast<const bf16x8*>(Vbase + ((size_t)(kt * 64 + kv2 + 1)) * DK_ + vc8);
#pragma unroll
            for (int j = 0; j < 8; ++j) {
                unsigned pk = (unsigned)(ushort_t)v0[j] | ((unsigned)(ushort_t)v1[j] << 16);
                *reinterpret_cast<unsigned*>(&Vt[(vc8 + j) * LDK + kv2]) = pk;
            }
        }
        __syncthreads();

        // ---- S = Q K^T (scaled), C layout: row=lg*4+r, col=lr ----
        f32x4 s[4];
#pragma unroll
        for (int nf = 0; nf < 4; ++nf) {
            f32x4 z = {};
            bf16x8 b0 = *reinterpret_cast<const bf16x8*>(&Ks[(nf * 16 + lr) * LDK + lg * 8]);
            bf16x8 b1 = *reinterpret_cast<const bf16x8*>(&Ks[(nf * 16 + lr) * LDK + 32 + lg * 8]);
            z = __builtin_amdgcn_mfma_f32_16x16x32_bf16(qf[0], b0, z, 0, 0, 0);
            z = __builtin_amdgcn_mfma_f32_16x16x32_bf16(qf[1], b1, z, 0, 0, 0);
            s[nf] = z;
        }

        // scale + causal mask (only the last tile straddles the diagonal)
#pragma unroll
        for (int nf = 0; nf < 4; ++nf)
#pragma unroll
            for (int r = 0; r < 4; ++r) s[nf][r] *= SCALE_;
        if (kt == ntiles - 1) {
#pragma unroll
            for (int nf = 0; nf < 4; ++nf) {
                const int kv = kt * 64 + nf * 16 + lr;
#pragma unroll
                for (int r = 0; r < 4; ++r) {
                    const int q = q0 + w * 16 + lg * 4 + r;
                    if (kv > q) s[nf][r] = -INFINITY;
                }
            }
        }

        // ---- online softmax ----
        float mn[4], corr[4], psum[4];
#pragma unroll
        for (int r = 0; r < 4; ++r) {
            float mx = fmaxf(fmaxf(s[0][r], s[1][r]), fmaxf(s[2][r], s[3][r]));
#pragma unroll
            for (int off = 8; off; off >>= 1) mx = fmaxf(mx, __shfl_xor(mx, off, 64));
            mn[r] = fmaxf(mrow[r], mx);
            corr[r] = __expf(mrow[r] - mn[r]);
            mrow[r] = mn[r];
            psum[r] = 0.0f;
        }
#pragma unroll
        for (int nf = 0; nf < 4; ++nf)
#pragma unroll
            for (int r = 0; r < 4; ++r) {
                const float p = __expf(s[nf][r] - mn[r]);
                psum[r] += p;
                Pl[(w * 16 + lg * 4 + r) * LDK + nf * 16 + lr] = f2bf(p);
            }
#pragma unroll
        for (int r = 0; r < 4; ++r) {
#pragma unroll
            for (int off = 8; off; off >>= 1) psum[r] += __shfl_xor(psum[r], off, 64);
            lrow[r] = lrow[r] * corr[r] + psum[r];
        }
#pragma unroll
        for (int df = 0; df < 4; ++df)
#pragma unroll
            for (int r = 0; r < 4; ++r) acc[df][r] *= corr[r];
        __syncthreads();   // P visible to own wave's ds_reads; Ks reads done

        // ---- O += P V :  A = P[16][64] (LDS), B = Vt (k-contig reads) ----
#pragma unroll
        for (int df = 0; df < 4; ++df) {
#pragma unroll
            for (int kf = 0; kf < 2; ++kf) {
                bf16x8 pa = *reinterpret_cast<const bf16x8*>(&Pl[(w * 16 + lr) * LDK + kf * 32 + lg * 8]);
                bf16x8 vb = *reinterpret_cast<const bf16x8*>(&Vt[(df * 16 + lr) * LDK + kf * 32 + lg * 8]);
                acc[df] = __builtin_amdgcn_mfma_f32_16x16x32_bf16(pa, vb, acc[df], 0, 0, 0);
            }
        }
        __syncthreads();   // protect Ks/Vt before next stage
    }

    // ---- epilogue: O[b, s, h*64+dk] = acc / l ----
    const int bb = bh >> 4, h = bh & 15;
#pragma unroll
    for (int r = 0; r < 4; ++r) {
        const float inv = 1.0f / lrow[r];
        const int q = q0 + w * 16 + lg * 4 + r;
        ushort_t* Orow = O + ((size_t)bb * S_ + q) * D_ + h * DK_;
#pragma unroll
        for (int df = 0; df < 4; ++df)
            Orow[df * 16 + lr] = f2bf(acc[df][r] * inv);
    }
}

// ---------------------------------------------------------------------------
// Launch.  ws layout (bytes):
//   0       Xb   bf16 [8192][1024]   16 MiB
//   16 MiB  Wqb/Wkb/Wvb/Wob bf16     2 MiB each
//   24 MiB  Qb   bf16 [B,H,S,DK]     16 MiB
//   40 MiB  Kb                        16 MiB
//   56 MiB  Vb                        16 MiB
//   72 MiB  Ao   bf16 [8192][1024]   16 MiB
//   88 MiB  rope table float2[2048][32]  512 KiB
// ---------------------------------------------------------------------------
extern "C" void kernel_launch(void* const* d_in, const int* in_sizes, int n_in,
                              void* d_out, int out_size, void* d_ws, size_t ws_size,
                              hipStream_t stream) {
    const float* x  = (const float*)d_in[0];
    const int*   tp = (const int*)d_in[1];
    const float* Wq = (const float*)d_in[2];
    const float* Wk = (const float*)d_in[3];
    const float* Wv = (const float*)d_in[4];
    const float* Wo = (const float*)d_in[5];
    float* out = (float*)d_out;

    char* ws = (char*)d_ws;
    ushort_t* Xb  = (ushort_t*)(ws);
    ushort_t* Wqb = (ushort_t*)(ws + (16ull << 20));
    ushort_t* Wkb = (ushort_t*)(ws + (18ull << 20));
    ushort_t* Wvb = (ushort_t*)(ws + (20ull << 20));
    ushort_t* Wob = (ushort_t*)(ws + (22ull << 20));
    ushort_t* Qb  = (ushort_t*)(ws + (24ull << 20));
    ushort_t* Kb  = (ushort_t*)(ws + (40ull << 20));
    ushort_t* Vb  = (ushort_t*)(ws + (56ull << 20));
    ushort_t* Ao  = (ushort_t*)(ws + (72ull << 20));
    float2*   tab = (float2*)(ws + (88ull << 20));

    const int NX = B_ * S_ * D_;       // 8388608
    const int NW = D_ * D_;            // 1048576
    cast_f32_bf16<<<NX / 1024, 256, 0, stream>>>(x, Xb, NX);
    cast_f32_bf16<<<NW / 1024, 256, 0, stream>>>(Wq, Wqb, NW);
    cast_f32_bf16<<<NW / 1024, 256, 0, stream>>>(Wk, Wkb, NW);
    cast_f32_bf16<<<NW / 1024, 256, 0, stream>>>(Wv, Wvb, NW);
    cast_f32_bf16<<<NW / 1024, 256, 0, stream>>>(Wo, Wob, NW);
    build_rope<<<(S_ * 32) / 256, 256, 0, stream>>>(tp, tab);

    gemm_bf16<2><<<512, 256, 0, stream>>>(Xb, Wqb, tab, nullptr, Qb);
    gemm_bf16<2><<<512, 256, 0, stream>>>(Xb, Wkb, tab, nullptr, Kb);
    gemm_bf16<1><<<512, 256, 0, stream>>>(Xb, Wvb, tab, nullptr, Vb);

    attn_mfma<<<2048, 256, 0, stream>>>(Qb, Kb, Vb, Ao);

    gemm_bf16<0><<<512, 256, 0, stream>>>(Ao, Wob, tab, out, nullptr);
}